// Round 3
// baseline (912.122 us; speedup 1.0000x reference)
//
#include <hip/hip_runtime.h>
#include <stdint.h>

typedef unsigned long long u64;

#define B_ROWS 8192
#define K_BITS 4096
#define KW 64      // u64 words along K (4096/64)
#define KC 8       // u64 words per K-chunk staged in LDS (halved: residency lever)
#define KSTRIDE 10 // LDS row stride in u64 (80 B: 16B-aligned at even w, bank-spread)
#define BM 128
#define BN 128

// ---------------- init ----------------
__global__ void init_stats(int* sum0, u64* sq0, int* sum1, u64* sq1,
                           int* sum2, u64* sq2, int* smax, int* smin, float* esum) {
  int i = blockIdx.x * 256 + threadIdx.x;
  if (i < 4096) { sum0[i] = 0; sq0[i] = 0; sum1[i] = 0; sq1[i] = 0; }
  if (i < 1024) {
    sum2[i] = 0; sq2[i] = 0;
    smax[i] = (int)0x80000000; smin[i] = 0x7fffffff;
    esum[i] = 0.0f;
  }
}

// ---------------- binarize + bit-pack x ----------------
__global__ void pack_x(const float* __restrict__ x, u64* __restrict__ bits) {
  int idx = blockIdx.x * 256 + threadIdx.x;
  float v = x[idx];
  u64 m = __ballot(v >= 0.5f);
  if ((threadIdx.x & 63) == 0) bits[idx >> 6] = m;
}

// ---------------- binarize + transpose-pack W (K x N  ->  [N][KW] bits) --------
__global__ void pack_w(const float* __restrict__ W, u64* __restrict__ Wb,
                       int N, int nlog2) {
  int t = blockIdx.x * 256 + threadIdx.x;   // N*64 threads
  int n = t & (N - 1);
  int w = t >> nlog2;
  const float* p = W + (size_t)(w * 64) * N + n;
  u64 m = 0;
  #pragma unroll 8
  for (int b = 0; b < 64; b++)
    m |= (u64)(p[(size_t)b * N] >= 0.0f) << b;
  Wb[(size_t)n * KW + w] = m;
}

// xor + popcount-accumulate, pinned to exactly 2 VALU insts:
//   v_xor_b32 t, a, b ; v_bcnt_u32_b32 acc, t, acc
#define XNOR_STEP(acc, av, bv) do {                                   \
    unsigned _t;                                                      \
    asm("v_xor_b32 %0, %1, %2" : "=v"(_t) : "v"(av), "v"(bv));        \
    asm("v_bcnt_u32_b32 %0, %1, %0" : "+v"(acc) : "v"(_t));           \
  } while (0)

// ---------------- XNOR-popcount GEMM + fused column stats ----------------
// S[r][n] = 4096 - 2*popc(Ab[r] ^ Wb[n]); fused per-column sum / sum-sq / minmax.
// Inner loop is inline-asm pinned: 4x (v_xor_b32 + v_bcnt_u32_b32) per u64 pair,
// accumulators forced into arch VGPRs by the "v" constraints.
// KC=8 (20.5 KB LDS vs 36 KB): by-LDS residency cap 4 -> 8 WGs/CU, so occupancy
// becomes VGPR-limited. (256,2) keeps the proven VGPR-84 no-spill codegen;
// min-waves is only a regalloc promise, not a residency cap.
__global__ __launch_bounds__(256, 2)
void gemm_xnor(const u64* __restrict__ Ab, const u64* __restrict__ Wb,
               short* __restrict__ S, int N,
               int* __restrict__ colsum, u64* __restrict__ colsq,
               int* __restrict__ colmax, int* __restrict__ colmin, int dominmax) {
  __shared__ alignas(16) u64 As[BM][KSTRIDE];   // only [.][0..KC) used; 10 KiB
  __shared__ alignas(16) u64 Bs[BN][KSTRIDE];

  const int tid = threadIdx.x;
  const int tx = tid & 15, ty = tid >> 4;
  const int row0 = blockIdx.y * BM, col0 = blockIdx.x * BN;

  int acc[8][8];
  #pragma unroll
  for (int i = 0; i < 8; i++)
    #pragma unroll
    for (int j = 0; j < 8; j++) acc[i][j] = 0;

  for (int k0 = 0; k0 < KW; k0 += KC) {
    #pragma unroll
    for (int i = 0; i < 2; i++) {
      int idx = tid + i * 256;          // 0..511
      int r = idx >> 2, wp = (idx & 3) << 1;   // r in [0,128), wp in {0,2,4,6}
      *(ulonglong2*)&As[r][wp] = *(const ulonglong2*)&Ab[(size_t)(row0 + r) * KW + k0 + wp];
      *(ulonglong2*)&Bs[r][wp] = *(const ulonglong2*)&Wb[(size_t)(col0 + r) * KW + k0 + wp];
    }
    __syncthreads();
    #pragma unroll 1
    for (int w = 0; w < KC; w += 2) {
      uint4 a[8], b[8];               // ds_read_b128: 2 u64 per read
      #pragma unroll
      for (int i = 0; i < 8; i++) a[i] = *(const uint4*)&As[ty + 16 * i][w];
      #pragma unroll
      for (int j = 0; j < 8; j++) b[j] = *(const uint4*)&Bs[tx + 16 * j][w];
      #pragma unroll
      for (int j = 0; j < 8; j++) {
        #pragma unroll
        for (int i = 0; i < 8; i++) {
          XNOR_STEP(acc[i][j], a[i].x, b[j].x);
          XNOR_STEP(acc[i][j], a[i].y, b[j].y);
          XNOR_STEP(acc[i][j], a[i].z, b[j].z);
          XNOR_STEP(acc[i][j], a[i].w, b[j].w);
        }
      }
    }
    __syncthreads();
  }

  // epilogue: write s (int16) + per-thread column partials
  int ps[8], pq[8], mx[8], mn[8];
  #pragma unroll
  for (int j = 0; j < 8; j++) { ps[j] = 0; pq[j] = 0; mx[j] = -100000; mn[j] = 100000; }
  #pragma unroll
  for (int i = 0; i < 8; i++) {
    size_t rowoff = (size_t)(row0 + ty + 16 * i) * N + col0;
    #pragma unroll
    for (int j = 0; j < 8; j++) {
      int s = K_BITS - 2 * acc[i][j];
      S[rowoff + tx + 16 * j] = (short)s;
      ps[j] += s;
      pq[j] += s * s;                       // <= 8*4096^2 = 2^27, fits int32
      mx[j] = (s > mx[j]) ? s : mx[j];
      mn[j] = (s < mn[j]) ? s : mn[j];
    }
  }
  // reuse As/Bs LDS for reductions (10240 B each >= 16*128*4 = 8192 B needed)
  int (*redA)[BN] = (int(*)[BN])As;
  int (*redB)[BN] = (int(*)[BN])Bs;
  #pragma unroll
  for (int j = 0; j < 8; j++) { redA[ty][tx + 16 * j] = ps[j]; redB[ty][tx + 16 * j] = pq[j]; }
  __syncthreads();
  if (tid < BN) {
    int ssum = 0; long long sq = 0;
    #pragma unroll
    for (int t = 0; t < 16; t++) { ssum += redA[t][tid]; sq += (long long)redB[t][tid]; }
    atomicAdd(&colsum[col0 + tid], ssum);
    atomicAdd(&colsq[col0 + tid], (u64)sq);
  }
  if (dominmax) {
    __syncthreads();
    #pragma unroll
    for (int j = 0; j < 8; j++) { redA[ty][tx + 16 * j] = mx[j]; redB[ty][tx + 16 * j] = mn[j]; }
    __syncthreads();
    if (tid < BN) {
      int m1 = -100000, m2 = 100000;
      #pragma unroll
      for (int t = 0; t < 16; t++) {
        m1 = (redA[t][tid] > m1) ? redA[t][tid] : m1;
        m2 = (redB[t][tid] < m2) ? redB[t][tid] : m2;
      }
      atomicMax(&colmax[col0 + tid], m1);
      atomicMin(&colmin[col0 + tid], m2);
    }
  }
}

// ---------------- per-column scale c = gamma / sqrt(var + eps) ----------------
__global__ void stats01(const int* __restrict__ colsum, const u64* __restrict__ colsq,
                        const float* __restrict__ gamma, int layer, float* __restrict__ c) {
  int n = blockIdx.x * 256 + threadIdx.x;
  double mu  = (double)colsum[n] / 8192.0;
  double var = (double)colsq[n] / 8192.0 - mu * mu;
  c[n] = (float)((double)gamma[layer] / sqrt(var + 1e-5));
}

// ---------------- binarize BN output -> next-layer bits ----------------
__global__ void binarize_pack(const short* __restrict__ S, const int* __restrict__ colsum,
                              const float* __restrict__ c, const float* __restrict__ beta,
                              int layer, u64* __restrict__ bits) {
  int gwave = (blockIdx.x * 256 + threadIdx.x) >> 6;
  int lane = threadIdx.x & 63;
  int idx0 = (gwave << 7) + lane;
  int idx1 = idx0 + 64;
  int n0 = idx0 & (K_BITS - 1);
  int n1 = idx1 & (K_BITS - 1);
  float bv = beta[layer];
  int t0 = (int)S[idx0] * 8192 - colsum[n0];
  int t1 = (int)S[idx1] * 8192 - colsum[n1];
  float a0 = (float)t0 * c[n0] * (1.0f / 8192.0f) + bv;
  float a1 = (float)t1 * c[n1] * (1.0f / 8192.0f) + bv;
  u64 m0 = __ballot(a0 >= 0.0f);
  u64 m1 = __ballot(a1 >= 0.0f);
  if (lane == 0) {
    bits[(gwave << 1) + 0] = m0;
    bits[(gwave << 1) + 1] = m1;
  }
}

// ---------------- last-layer stats: scale + reference s for softmax ------------
__global__ void final_stats(const int* __restrict__ colsum, const u64* __restrict__ colsq,
                            const int* __restrict__ colmax, const int* __restrict__ colmin,
                            const float* __restrict__ gamma,
                            float* __restrict__ c, int* __restrict__ sref) {
  int n = blockIdx.x * 256 + threadIdx.x;  // 1024
  double mu  = (double)colsum[n] / 8192.0;
  double var = (double)colsq[n] / 8192.0 - mu * mu;
  float cv = (float)((double)gamma[2] / sqrt(var + 1e-5));
  c[n] = cv;
  sref[n] = (cv >= 0.0f) ? colmax[n] : colmin[n];   // argmax of a per column
}

// ---------------- softmax over batch dim (axis 0), per column ----------------
__global__ void softmax_p1(const short* __restrict__ S2, const int* __restrict__ sref,
                           const float* __restrict__ c, float* __restrict__ out,
                           float* __restrict__ esum) {
  int n  = blockIdx.x * 256 + threadIdx.x;   // gridDim.x = 4 -> n in [0,1024)
  int r0 = blockIdx.y * 128;
  float cs = c[n]; int sr = sref[n];
  float acc = 0.0f;
  for (int r = 0; r < 128; r++) {
    size_t idx = (size_t)(r0 + r) * 1024 + n;
    float e = __expf((float)((int)S2[idx] - sr) * cs);   // (a - amax), always <= 0
    out[idx] = e;
    acc += e;
  }
  atomicAdd(&esum[n], acc);
}

__global__ void softmax_p2(float* __restrict__ out, const float* __restrict__ esum) {
  int idx = blockIdx.x * 256 + threadIdx.x;
  out[idx] /= esum[idx & 1023];
}

// ---------------- launcher ----------------
extern "C" void kernel_launch(void* const* d_in, const int* in_sizes, int n_in,
                              void* d_out, int out_size, void* d_ws, size_t ws_size,
                              hipStream_t stream) {
  const float* x     = (const float*)d_in[0];
  const float* W0    = (const float*)d_in[1];
  const float* W1    = (const float*)d_in[2];
  const float* W2    = (const float*)d_in[3];
  const float* gamma = (const float*)d_in[4];
  const float* beta  = (const float*)d_in[5];
  float* out = (float*)d_out;

  char* ws = (char*)d_ws;
  u64*   bitsA = (u64*)(ws + 0);                  // 4 MiB  (8192 x 64 u64)
  u64*   bitsB = (u64*)(ws + (4ull  << 20));      // 4 MiB
  u64*   Wb0   = (u64*)(ws + (8ull  << 20));      // 2 MiB  (4096 x 64 u64)
  u64*   Wb1   = (u64*)(ws + (10ull << 20));      // 2 MiB
  u64*   Wb2   = (u64*)(ws + (12ull << 20));      // 0.5 MiB (1024 x 64 u64)
  short* S     = (short*)(ws + (16ull << 20));    // 64 MiB (8192 x 4096 int16)
  char*  st    = ws + (80ull << 20);
  int*   sum0 = (int*)(st);                        // 16 KB
  u64*   sq0  = (u64*)(st + 16 * 1024);            // 32 KB
  int*   sum1 = (int*)(st + 48 * 1024);            // 16 KB
  u64*   sq1  = (u64*)(st + 64 * 1024);            // 32 KB
  int*   sum2 = (int*)(st + 96 * 1024);            // 4 KB
  u64*   sq2  = (u64*)(st + 100 * 1024);           // 8 KB
  int*   smax = (int*)(st + 108 * 1024);           // 4 KB
  int*   smin = (int*)(st + 112 * 1024);           // 4 KB
  float* c0   = (float*)(st + 116 * 1024);         // 16 KB
  float* c1   = (float*)(st + 132 * 1024);         // 16 KB
  float* c2   = (float*)(st + 148 * 1024);         // 4 KB
  int*   sref = (int*)(st + 152 * 1024);           // 4 KB
  float* esum = (float*)(st + 156 * 1024);         // 4 KB

  init_stats<<<16, 256, 0, stream>>>(sum0, sq0, sum1, sq1, sum2, sq2, smax, smin, esum);
  pack_x<<<(B_ROWS * K_BITS) / 256, 256, 0, stream>>>(x, bitsA);
  pack_w<<<(4096 * 64) / 256, 256, 0, stream>>>(W0, Wb0, 4096, 12);
  pack_w<<<(4096 * 64) / 256, 256, 0, stream>>>(W1, Wb1, 4096, 12);
  pack_w<<<(1024 * 64) / 256, 256, 0, stream>>>(W2, Wb2, 1024, 10);

  // layer 0
  gemm_xnor<<<dim3(32, 64), 256, 0, stream>>>(bitsA, Wb0, S, 4096, sum0, sq0, nullptr, nullptr, 0);
  stats01<<<16, 256, 0, stream>>>(sum0, sq0, gamma, 0, c0);
  binarize_pack<<<(B_ROWS * 4096) / 512, 256, 0, stream>>>(S, sum0, c0, beta, 0, bitsB);

  // layer 1
  gemm_xnor<<<dim3(32, 64), 256, 0, stream>>>(bitsB, Wb1, S, 4096, sum1, sq1, nullptr, nullptr, 0);
  stats01<<<16, 256, 0, stream>>>(sum1, sq1, gamma, 1, c1);
  binarize_pack<<<(B_ROWS * 4096) / 512, 256, 0, stream>>>(S, sum1, c1, beta, 1, bitsA);

  // layer 2 (N=1024) + batch-dim softmax
  gemm_xnor<<<dim3(8, 64), 256, 0, stream>>>(bitsA, Wb2, S, 1024, sum2, sq2, smax, smin, 1);
  final_stats<<<4, 256, 0, stream>>>(sum2, sq2, smax, smin, gamma, c2, sref);
  softmax_p1<<<dim3(4, 64), 256, 0, stream>>>(S, sref, c2, out, esum);
  softmax_p2<<<(B_ROWS * 1024) / 256, 256, 0, stream>>>(out, esum);
}

// Round 4
// 898.160 us; speedup vs baseline: 1.0155x; 1.0155x over previous
//
#include <hip/hip_runtime.h>
#include <stdint.h>

typedef unsigned long long u64;
typedef int v4i  __attribute__((ext_vector_type(4)));
typedef int v16i __attribute__((ext_vector_type(16)));

#define B_ROWS 8192
#define K_BITS 4096
#define KW 64      // u64 words along K (4096/64)
#define GBM 256    // block tile rows
#define GBN 256    // block tile cols

// ---------------- init ----------------
__global__ void init_stats(int* sum0, u64* sq0, int* sum1, u64* sq1,
                           int* sum2, u64* sq2, int* smax, int* smin, float* esum,
                           int* rp0, int* rp1, int* rp2, int* cp0, int* cp1, int* cp2) {
  int i = blockIdx.x * 256 + threadIdx.x;   // grid 32x256 = 8192
  if (i < 8192) { rp0[i] = 0; rp1[i] = 0; rp2[i] = 0; }
  if (i < 4096) { sum0[i] = 0; sq0[i] = 0; sum1[i] = 0; sq1[i] = 0; cp0[i] = 0; cp1[i] = 0; }
  if (i < 1024) {
    sum2[i] = 0; sq2[i] = 0; cp2[i] = 0;
    smax[i] = (int)0x80000000; smin[i] = 0x7fffffff;
    esum[i] = 0.0f;
  }
}

// ---------------- binarize + bit-pack x (+ fused row-popcount) ----------------
__global__ void pack_x(const float* __restrict__ x, u64* __restrict__ bits,
                       int* __restrict__ rp) {
  int idx = blockIdx.x * 256 + threadIdx.x;
  float v = x[idx];
  u64 m = __ballot(v >= 0.5f);
  if ((threadIdx.x & 63) == 0) {
    bits[idx >> 6] = m;
    atomicAdd(&rp[idx >> 12], (int)__popcll(m));   // row = idx/4096
  }
}

// ------- binarize + transpose-pack W (K x N -> [N][KW] bits) + col-popcount ----
__global__ void pack_w(const float* __restrict__ W, u64* __restrict__ Wb,
                       int N, int nlog2, int* __restrict__ cp) {
  int t = blockIdx.x * 256 + threadIdx.x;   // N*64 threads
  int n = t & (N - 1);
  int w = t >> nlog2;
  const float* p = W + (size_t)(w * 64) * N + n;
  u64 m = 0;
  #pragma unroll 8
  for (int b = 0; b < 64; b++)
    m |= (u64)(p[(size_t)b * N] >= 0.0f) << b;
  Wb[(size_t)n * KW + w] = m;
  atomicAdd(&cp[n], (int)__popcll(m));
}

// 16 bits (0/1) -> 16 i8 bytes in 4 VGPRs. bit q*4+j -> reg q, byte j.
// spread: (nib * 0x00204081) & 0x01010101 puts nibble bit i into byte i LSB.
__device__ __forceinline__ v4i unpack16(unsigned word, int shbase) {
  v4i r;
  #pragma unroll
  for (int q = 0; q < 4; q++) {
    unsigned nib = (word >> (shbase + 4 * q)) & 15u;
    r[q] = (int)(__umul24(nib, 0x00204081u) & 0x01010101u);
  }
  return r;
}

// ---------------- MFMA-i8 binary GEMM + fused column stats ----------------
// s[r][n] = 4*dot01 - 2*rowpop[r] - 2*colpop[n] + 4096  (a,w in {-1,+1})
// 256x256 tile, 512 thr = 8 waves (2M x 4N); per wave 128x64 out = 4x2 MFMA
// tiles of 32x32, acc 128 i32/lane. Bits staged in LDS (8KB/chunk of K=128),
// register-double-buffered global loads; fragments unpacked in-register.
// A/B frag layout: lane l -> row/col = l&31, k = 16*(l>>5)+e, e=4*reg+byte.
// C/D layout (m74/m101-verified): col=lane&31, row=(reg&3)+8*(reg>>2)+4*(lane>>5).
__global__ __launch_bounds__(512, 2)
void gemm_mfma(const u64* __restrict__ Ab, const u64* __restrict__ Wb,
               short* __restrict__ S, int N,
               const int* __restrict__ rp, const int* __restrict__ cp,
               int* __restrict__ colsum, u64* __restrict__ colsq,
               int* __restrict__ colmax, int* __restrict__ colmin, int dominmax) {
  __shared__ alignas(16) u64 AsB[256][2];   // 4 KB: bit chunk (K=128) for A rows
  __shared__ alignas(16) u64 BsB[256][2];   // 4 KB: bit chunk for B cols
  __shared__ int rp_s[256];
  __shared__ int redS[4][256];
  __shared__ int redQ[4][256];

  const int tid  = threadIdx.x;
  const int lane = tid & 63;
  const int wid  = tid >> 6;          // 0..7
  const int wm   = wid >> 2;          // 0..1 (M)
  const int wn   = wid & 3;           // 0..3 (N)
  const int half = lane >> 5;         // 0..1
  const int l31  = lane & 31;
  const int row0 = blockIdx.y * GBM, col0 = blockIdx.x * GBN;

  if (tid < 256) rp_s[tid] = rp[row0 + tid];

  v16i acc[4][2];
  #pragma unroll
  for (int mt = 0; mt < 4; mt++)
    #pragma unroll
    for (int nt = 0; nt < 2; nt++)
      #pragma unroll
      for (int e = 0; e < 16; e++) acc[mt][nt][e] = 0;

  // staging: thread t owns (row=t>>1, word=t&1) of each 2-u64 chunk
  const int srow = tid >> 1, sw = tid & 1;
  const u64* aptr = Ab + (size_t)(row0 + srow) * KW + sw;
  const u64* bptr = Wb + (size_t)(col0 + srow) * KW + sw;

  u64 areg = aptr[0], breg = bptr[0];

  for (int ch = 0; ch < 32; ch++) {
    AsB[srow][sw] = areg;
    BsB[srow][sw] = breg;
    __syncthreads();
    if (ch < 31) { areg = aptr[2 * (ch + 1)]; breg = bptr[2 * (ch + 1)]; }
    // pull this wave's bit words to registers, then release LDS at barrier
    uint4 abits[4]; uint4 bbits[2];
    #pragma unroll
    for (int mt = 0; mt < 4; mt++)
      abits[mt] = *(const uint4*)&AsB[wm * 128 + mt * 32 + l31][0];
    #pragma unroll
    for (int nt = 0; nt < 2; nt++)
      bbits[nt] = *(const uint4*)&BsB[wn * 64 + nt * 32 + l31][0];
    __syncthreads();
    // 4 k-steps of 32; compute is register-only (overlaps next-chunk staging)
    #pragma unroll
    for (int ks = 0; ks < 4; ks++) {
      v4i afrag[4], bfrag[2];
      #pragma unroll
      for (int mt = 0; mt < 4; mt++) {
        unsigned wa = (ks == 0) ? abits[mt].x : (ks == 1) ? abits[mt].y
                    : (ks == 2) ? abits[mt].z : abits[mt].w;
        afrag[mt] = unpack16(wa, half * 16);
      }
      #pragma unroll
      for (int nt = 0; nt < 2; nt++) {
        unsigned wb = (ks == 0) ? bbits[nt].x : (ks == 1) ? bbits[nt].y
                    : (ks == 2) ? bbits[nt].z : bbits[nt].w;
        bfrag[nt] = unpack16(wb, half * 16);
      }
      #pragma unroll
      for (int mt = 0; mt < 4; mt++)
        #pragma unroll
        for (int nt = 0; nt < 2; nt++)
          acc[mt][nt] = __builtin_amdgcn_mfma_i32_32x32x32_i8(
              afrag[mt], bfrag[nt], acc[mt][nt], 0, 0, 0);
    }
  }

  // ---- epilogue: s = 4*acc - 2*rp - 2*cp + 4096; write S + column partials ----
  int cpv[2];
  #pragma unroll
  for (int nt = 0; nt < 2; nt++) cpv[nt] = cp[col0 + wn * 64 + nt * 32 + l31];

  int ps[2], pq[2], mx[2], mn[2];
  #pragma unroll
  for (int nt = 0; nt < 2; nt++) { ps[nt] = 0; pq[nt] = 0; mx[nt] = -100000; mn[nt] = 100000; }

  #pragma unroll
  for (int mt = 0; mt < 4; mt++) {
    #pragma unroll
    for (int reg = 0; reg < 16; reg++) {
      int rloc = wm * 128 + mt * 32 + (reg & 3) + 8 * (reg >> 2) + 4 * half;
      int rpv  = rp_s[rloc];
      size_t rowoff = (size_t)(row0 + rloc) * N + col0;
      #pragma unroll
      for (int nt = 0; nt < 2; nt++) {
        int s = 4 * acc[mt][nt][reg] - 2 * rpv - 2 * cpv[nt] + K_BITS;
        S[rowoff + wn * 64 + nt * 32 + l31] = (short)s;
        ps[nt] += s;
        pq[nt] += s * s;   // 64 * 4096^2 = 1.07e9 < 2^31
        mx[nt] = (s > mx[nt]) ? s : mx[nt];
        mn[nt] = (s < mn[nt]) ? s : mn[nt];
      }
    }
  }

  const int contrib = wm * 2 + half;   // 4 partials per block-column
  #pragma unroll
  for (int nt = 0; nt < 2; nt++) {
    redS[contrib][wn * 64 + nt * 32 + l31] = ps[nt];
    redQ[contrib][wn * 64 + nt * 32 + l31] = pq[nt];
  }
  __syncthreads();
  if (tid < 256) {
    int ssum = 0; long long sq = 0;
    #pragma unroll
    for (int t = 0; t < 4; t++) { ssum += redS[t][tid]; sq += (long long)redQ[t][tid]; }
    atomicAdd(&colsum[col0 + tid], ssum);
    atomicAdd(&colsq[col0 + tid], (u64)sq);
  }
  if (dominmax) {
    __syncthreads();
    #pragma unroll
    for (int nt = 0; nt < 2; nt++) {
      redS[contrib][wn * 64 + nt * 32 + l31] = mx[nt];
      redQ[contrib][wn * 64 + nt * 32 + l31] = mn[nt];
    }
    __syncthreads();
    if (tid < 256) {
      int m1 = -100000, m2 = 100000;
      #pragma unroll
      for (int t = 0; t < 4; t++) {
        m1 = (redS[t][tid] > m1) ? redS[t][tid] : m1;
        m2 = (redQ[t][tid] < m2) ? redQ[t][tid] : m2;
      }
      atomicMax(&colmax[col0 + tid], m1);
      atomicMin(&colmin[col0 + tid], m2);
    }
  }
}

// ---------------- per-column scale c = gamma / sqrt(var + eps) ----------------
__global__ void stats01(const int* __restrict__ colsum, const u64* __restrict__ colsq,
                        const float* __restrict__ gamma, int layer, float* __restrict__ c) {
  int n = blockIdx.x * 256 + threadIdx.x;
  double mu  = (double)colsum[n] / 8192.0;
  double var = (double)colsq[n] / 8192.0 - mu * mu;
  c[n] = (float)((double)gamma[layer] / sqrt(var + 1e-5));
}

// -------- binarize BN output -> next-layer bits (+ fused row-popcount) --------
__global__ void binarize_pack(const short* __restrict__ S, const int* __restrict__ colsum,
                              const float* __restrict__ c, const float* __restrict__ beta,
                              int layer, u64* __restrict__ bits, int* __restrict__ rpn) {
  int gwave = (blockIdx.x * 256 + threadIdx.x) >> 6;
  int lane = threadIdx.x & 63;
  int idx0 = (gwave << 7) + lane;
  int idx1 = idx0 + 64;
  int n0 = idx0 & (K_BITS - 1);
  int n1 = idx1 & (K_BITS - 1);
  float bv = beta[layer];
  int t0 = (int)S[idx0] * 8192 - colsum[n0];
  int t1 = (int)S[idx1] * 8192 - colsum[n1];
  float a0 = (float)t0 * c[n0] * (1.0f / 8192.0f) + bv;
  float a1 = (float)t1 * c[n1] * (1.0f / 8192.0f) + bv;
  u64 m0 = __ballot(a0 >= 0.0f);
  u64 m1 = __ballot(a1 >= 0.0f);
  if (lane == 0) {
    bits[(gwave << 1) + 0] = m0;
    bits[(gwave << 1) + 1] = m1;
    atomicAdd(&rpn[idx0 >> 12], (int)(__popcll(m0) + __popcll(m1)));  // same row
  }
}

// ---------------- last-layer stats: scale + reference s for softmax ------------
__global__ void final_stats(const int* __restrict__ colsum, const u64* __restrict__ colsq,
                            const int* __restrict__ colmax, const int* __restrict__ colmin,
                            const float* __restrict__ gamma,
                            float* __restrict__ c, int* __restrict__ sref) {
  int n = blockIdx.x * 256 + threadIdx.x;  // 1024
  double mu  = (double)colsum[n] / 8192.0;
  double var = (double)colsq[n] / 8192.0 - mu * mu;
  float cv = (float)((double)gamma[2] / sqrt(var + 1e-5));
  c[n] = cv;
  sref[n] = (cv >= 0.0f) ? colmax[n] : colmin[n];   // argmax of a per column
}

// ---------------- softmax over batch dim (axis 0), per column ----------------
__global__ void softmax_p1(const short* __restrict__ S2, const int* __restrict__ sref,
                           const float* __restrict__ c, float* __restrict__ out,
                           float* __restrict__ esum) {
  int n  = blockIdx.x * 256 + threadIdx.x;   // gridDim.x = 4 -> n in [0,1024)
  int r0 = blockIdx.y * 128;
  float cs = c[n]; int sr = sref[n];
  float acc = 0.0f;
  for (int r = 0; r < 128; r++) {
    size_t idx = (size_t)(r0 + r) * 1024 + n;
    float e = __expf((float)((int)S2[idx] - sr) * cs);   // (a - amax), always <= 0
    out[idx] = e;
    acc += e;
  }
  atomicAdd(&esum[n], acc);
}

__global__ void softmax_p2(float* __restrict__ out, const float* __restrict__ esum) {
  int idx = blockIdx.x * 256 + threadIdx.x;
  out[idx] /= esum[idx & 1023];
}

// ---------------- launcher ----------------
extern "C" void kernel_launch(void* const* d_in, const int* in_sizes, int n_in,
                              void* d_out, int out_size, void* d_ws, size_t ws_size,
                              hipStream_t stream) {
  const float* x     = (const float*)d_in[0];
  const float* W0    = (const float*)d_in[1];
  const float* W1    = (const float*)d_in[2];
  const float* W2    = (const float*)d_in[3];
  const float* gamma = (const float*)d_in[4];
  const float* beta  = (const float*)d_in[5];
  float* out = (float*)d_out;

  char* ws = (char*)d_ws;
  u64*   bitsA = (u64*)(ws + 0);                  // 4 MiB  (8192 x 64 u64)
  u64*   bitsB = (u64*)(ws + (4ull  << 20));      // 4 MiB
  u64*   Wb0   = (u64*)(ws + (8ull  << 20));      // 2 MiB  (4096 x 64 u64)
  u64*   Wb1   = (u64*)(ws + (10ull << 20));      // 2 MiB
  u64*   Wb2   = (u64*)(ws + (12ull << 20));      // 0.5 MiB (1024 x 64 u64)
  short* S     = (short*)(ws + (16ull << 20));    // 64 MiB (8192 x 4096 int16)
  char*  st    = ws + (80ull << 20);
  int*   sum0 = (int*)(st);                        // 16 KB
  u64*   sq0  = (u64*)(st + 16 * 1024);            // 32 KB
  int*   sum1 = (int*)(st + 48 * 1024);            // 16 KB
  u64*   sq1  = (u64*)(st + 64 * 1024);            // 32 KB
  int*   sum2 = (int*)(st + 96 * 1024);            // 4 KB
  u64*   sq2  = (u64*)(st + 100 * 1024);           // 8 KB
  int*   smax = (int*)(st + 108 * 1024);           // 4 KB
  int*   smin = (int*)(st + 112 * 1024);           // 4 KB
  float* c0   = (float*)(st + 116 * 1024);         // 16 KB
  float* c1   = (float*)(st + 132 * 1024);         // 16 KB
  float* c2   = (float*)(st + 148 * 1024);         // 4 KB
  int*   sref = (int*)(st + 152 * 1024);           // 4 KB
  float* esum = (float*)(st + 156 * 1024);         // 4 KB
  int*   rp0  = (int*)(st + 160 * 1024);           // 32 KB (row popcount, layer0 in)
  int*   rp1  = (int*)(st + 192 * 1024);           // 32 KB (layer1 in)
  int*   rp2  = (int*)(st + 224 * 1024);           // 32 KB (layer2 in)
  int*   cp0  = (int*)(st + 256 * 1024);           // 16 KB (col popcount W0)
  int*   cp1  = (int*)(st + 272 * 1024);           // 16 KB
  int*   cp2  = (int*)(st + 288 * 1024);           // 4 KB

  init_stats<<<32, 256, 0, stream>>>(sum0, sq0, sum1, sq1, sum2, sq2, smax, smin, esum,
                                     rp0, rp1, rp2, cp0, cp1, cp2);
  pack_x<<<(B_ROWS * K_BITS) / 256, 256, 0, stream>>>(x, bitsA, rp0);
  pack_w<<<(4096 * 64) / 256, 256, 0, stream>>>(W0, Wb0, 4096, 12, cp0);
  pack_w<<<(4096 * 64) / 256, 256, 0, stream>>>(W1, Wb1, 4096, 12, cp1);
  pack_w<<<(1024 * 64) / 256, 256, 0, stream>>>(W2, Wb2, 1024, 10, cp2);

  // layer 0
  gemm_mfma<<<dim3(16, 32), 512, 0, stream>>>(bitsA, Wb0, S, 4096, rp0, cp0,
                                              sum0, sq0, nullptr, nullptr, 0);
  stats01<<<16, 256, 0, stream>>>(sum0, sq0, gamma, 0, c0);
  binarize_pack<<<(B_ROWS * 4096) / 512, 256, 0, stream>>>(S, sum0, c0, beta, 0, bitsB, rp1);

  // layer 1
  gemm_mfma<<<dim3(16, 32), 512, 0, stream>>>(bitsB, Wb1, S, 4096, rp1, cp1,
                                              sum1, sq1, nullptr, nullptr, 0);
  stats01<<<16, 256, 0, stream>>>(sum1, sq1, gamma, 1, c1);
  binarize_pack<<<(B_ROWS * 4096) / 512, 256, 0, stream>>>(S, sum1, c1, beta, 1, bitsA, rp2);

  // layer 2 (N=1024) + batch-dim softmax
  gemm_mfma<<<dim3(4, 32), 512, 0, stream>>>(bitsA, Wb2, S, 1024, rp2, cp2,
                                             sum2, sq2, smax, smin, 1);
  final_stats<<<4, 256, 0, stream>>>(sum2, sq2, smax, smin, gamma, c2, sref);
  softmax_p1<<<dim3(4, 64), 256, 0, stream>>>(S, sref, c2, out, esum);
  softmax_p2<<<(B_ROWS * 1024) / 256, 256, 0, stream>>>(out, esum);
}

// Round 5
// 772.224 us; speedup vs baseline: 1.1812x; 1.1631x over previous
//
#include <hip/hip_runtime.h>
#include <stdint.h>

typedef unsigned long long u64;
typedef int v4i  __attribute__((ext_vector_type(4)));
typedef int v16i __attribute__((ext_vector_type(16)));

#define B_ROWS 8192
#define K_BITS 4096
#define KW 64      // u64 words along K (4096/64)
#define GBM 256    // block tile rows
#define GBN 256    // block tile cols

// ---------------- init ----------------
__global__ void init_stats(int* sum0, u64* sq0, int* sum1, u64* sq1,
                           int* sum2, u64* sq2, int* smax, int* smin, float* esum,
                           int* rp0, int* rp1, int* rp2, int* cp0, int* cp1, int* cp2) {
  int i = blockIdx.x * 256 + threadIdx.x;   // grid 32x256 = 8192
  if (i < 8192) { rp0[i] = 0; rp1[i] = 0; rp2[i] = 0; }
  if (i < 4096) { sum0[i] = 0; sq0[i] = 0; sum1[i] = 0; sq1[i] = 0; cp0[i] = 0; cp1[i] = 0; }
  if (i < 1024) {
    sum2[i] = 0; sq2[i] = 0; cp2[i] = 0;
    smax[i] = (int)0x80000000; smin[i] = 0x7fffffff;
    esum[i] = 0.0f;
  }
}

// ---------------- binarize + bit-pack x (+ fused row-popcount) ----------------
// One block per row: thread t packs 16 consecutive floats (4x float4, 16B/lane)
// into a ushort; little-endian ushort view of the u64 bit array preserves the
// layout bits[row*64 + col/64] bit (col&63). Row popcount: wave shfl-reduce +
// LDS, single direct store (no atomics).
__global__ __launch_bounds__(256)
void pack_x(const float* __restrict__ x, u64* __restrict__ bits,
            int* __restrict__ rp) {
  const int row = blockIdx.x;
  const int t = threadIdx.x;
  const float4* p = (const float4*)(x + (size_t)row * K_BITS + 16 * t);
  unsigned m = 0;
  #pragma unroll
  for (int q = 0; q < 4; q++) {
    float4 v = p[q];
    m |= (unsigned)(v.x >= 0.5f) << (4 * q + 0);
    m |= (unsigned)(v.y >= 0.5f) << (4 * q + 1);
    m |= (unsigned)(v.z >= 0.5f) << (4 * q + 2);
    m |= (unsigned)(v.w >= 0.5f) << (4 * q + 3);
  }
  ((unsigned short*)bits)[(size_t)row * 256 + t] = (unsigned short)m;
  int pc = __popc(m);
  #pragma unroll
  for (int off = 32; off; off >>= 1) pc += __shfl_down(pc, off);   // wave64 reduce
  __shared__ int acc4[4];
  if ((t & 63) == 0) acc4[t >> 6] = pc;
  __syncthreads();
  if (t == 0) rp[row] = acc4[0] + acc4[1] + acc4[2] + acc4[3];
}

// ------- binarize + transpose-pack W (K x N -> [N][KW] bits) + col-popcount ----
__global__ void pack_w(const float* __restrict__ W, u64* __restrict__ Wb,
                       int N, int nlog2, int* __restrict__ cp) {
  int t = blockIdx.x * 256 + threadIdx.x;   // N*64 threads
  int n = t & (N - 1);
  int w = t >> nlog2;
  const float* p = W + (size_t)(w * 64) * N + n;
  u64 m = 0;
  #pragma unroll 8
  for (int b = 0; b < 64; b++)
    m |= (u64)(p[(size_t)b * N] >= 0.0f) << b;
  Wb[(size_t)n * KW + w] = m;
  atomicAdd(&cp[n], (int)__popcll(m));
}

// 16 bits (0/1) -> 16 i8 bytes in 4 VGPRs. bit q*4+j -> reg q, byte j.
// spread: (nib * 0x00204081) & 0x01010101 puts nibble bit i into byte i LSB.
__device__ __forceinline__ v4i unpack16(unsigned word, int shbase) {
  v4i r;
  #pragma unroll
  for (int q = 0; q < 4; q++) {
    unsigned nib = (word >> (shbase + 4 * q)) & 15u;
    r[q] = (int)(__umul24(nib, 0x00204081u) & 0x01010101u);
  }
  return r;
}

// ---------------- MFMA-i8 binary GEMM + fused column stats ----------------
// s[r][n] = 4*dot01 - 2*rowpop[r] - 2*colpop[n] + 4096  (a,w in {-1,+1})
// 256x256 tile, 512 thr = 8 waves (2M x 4N); per wave 128x64 out = 4x2 MFMA
// tiles of 32x32, acc 128 i32/lane. Bits staged in LDS (8KB/chunk of K=128),
// register-double-buffered global loads; fragments unpacked in-register.
// A/B frag layout: lane l -> row/col = l&31, k = 16*(l>>5)+e, e=4*reg+byte.
// C/D layout (m74/m101-verified): col=lane&31, row=(reg&3)+8*(reg>>2)+4*(lane>>5).
__global__ __launch_bounds__(512, 2)
void gemm_mfma(const u64* __restrict__ Ab, const u64* __restrict__ Wb,
               short* __restrict__ S, int N,
               const int* __restrict__ rp, const int* __restrict__ cp,
               int* __restrict__ colsum, u64* __restrict__ colsq,
               int* __restrict__ colmax, int* __restrict__ colmin, int dominmax) {
  __shared__ alignas(16) u64 AsB[256][2];   // 4 KB: bit chunk (K=128) for A rows
  __shared__ alignas(16) u64 BsB[256][2];   // 4 KB: bit chunk for B cols
  __shared__ int rp_s[256];
  __shared__ int redS[4][256];
  __shared__ int redQ[4][256];

  const int tid  = threadIdx.x;
  const int lane = tid & 63;
  const int wid  = tid >> 6;          // 0..7
  const int wm   = wid >> 2;          // 0..1 (M)
  const int wn   = wid & 3;           // 0..3 (N)
  const int half = lane >> 5;         // 0..1
  const int l31  = lane & 31;
  const int row0 = blockIdx.y * GBM, col0 = blockIdx.x * GBN;

  if (tid < 256) rp_s[tid] = rp[row0 + tid];

  v16i acc[4][2];
  #pragma unroll
  for (int mt = 0; mt < 4; mt++)
    #pragma unroll
    for (int nt = 0; nt < 2; nt++)
      #pragma unroll
      for (int e = 0; e < 16; e++) acc[mt][nt][e] = 0;

  // staging: thread t owns (row=t>>1, word=t&1) of each 2-u64 chunk
  const int srow = tid >> 1, sw = tid & 1;
  const u64* aptr = Ab + (size_t)(row0 + srow) * KW + sw;
  const u64* bptr = Wb + (size_t)(col0 + srow) * KW + sw;

  u64 areg = aptr[0], breg = bptr[0];

  for (int ch = 0; ch < 32; ch++) {
    AsB[srow][sw] = areg;
    BsB[srow][sw] = breg;
    __syncthreads();
    if (ch < 31) { areg = aptr[2 * (ch + 1)]; breg = bptr[2 * (ch + 1)]; }
    // pull this wave's bit words to registers, then release LDS at barrier
    uint4 abits[4]; uint4 bbits[2];
    #pragma unroll
    for (int mt = 0; mt < 4; mt++)
      abits[mt] = *(const uint4*)&AsB[wm * 128 + mt * 32 + l31][0];
    #pragma unroll
    for (int nt = 0; nt < 2; nt++)
      bbits[nt] = *(const uint4*)&BsB[wn * 64 + nt * 32 + l31][0];
    __syncthreads();
    // 4 k-steps of 32; compute is register-only (overlaps next-chunk staging)
    #pragma unroll
    for (int ks = 0; ks < 4; ks++) {
      v4i afrag[4], bfrag[2];
      #pragma unroll
      for (int mt = 0; mt < 4; mt++) {
        unsigned wa = (ks == 0) ? abits[mt].x : (ks == 1) ? abits[mt].y
                    : (ks == 2) ? abits[mt].z : abits[mt].w;
        afrag[mt] = unpack16(wa, half * 16);
      }
      #pragma unroll
      for (int nt = 0; nt < 2; nt++) {
        unsigned wb = (ks == 0) ? bbits[nt].x : (ks == 1) ? bbits[nt].y
                    : (ks == 2) ? bbits[nt].z : bbits[nt].w;
        bfrag[nt] = unpack16(wb, half * 16);
      }
      #pragma unroll
      for (int mt = 0; mt < 4; mt++)
        #pragma unroll
        for (int nt = 0; nt < 2; nt++)
          acc[mt][nt] = __builtin_amdgcn_mfma_i32_32x32x32_i8(
              afrag[mt], bfrag[nt], acc[mt][nt], 0, 0, 0);
    }
  }

  // ---- epilogue: s = 4*acc - 2*rp - 2*cp + 4096; write S + column partials ----
  int cpv[2];
  #pragma unroll
  for (int nt = 0; nt < 2; nt++) cpv[nt] = cp[col0 + wn * 64 + nt * 32 + l31];

  int ps[2], pq[2], mx[2], mn[2];
  #pragma unroll
  for (int nt = 0; nt < 2; nt++) { ps[nt] = 0; pq[nt] = 0; mx[nt] = -100000; mn[nt] = 100000; }

  #pragma unroll
  for (int mt = 0; mt < 4; mt++) {
    #pragma unroll
    for (int reg = 0; reg < 16; reg++) {
      int rloc = wm * 128 + mt * 32 + (reg & 3) + 8 * (reg >> 2) + 4 * half;
      int rpv  = rp_s[rloc];
      size_t rowoff = (size_t)(row0 + rloc) * N + col0;
      #pragma unroll
      for (int nt = 0; nt < 2; nt++) {
        int s = 4 * acc[mt][nt][reg] - 2 * rpv - 2 * cpv[nt] + K_BITS;
        S[rowoff + wn * 64 + nt * 32 + l31] = (short)s;
        ps[nt] += s;
        pq[nt] += s * s;   // 64 * 4096^2 = 1.07e9 < 2^31
        mx[nt] = (s > mx[nt]) ? s : mx[nt];
        mn[nt] = (s < mn[nt]) ? s : mn[nt];
      }
    }
  }

  const int contrib = wm * 2 + half;   // 4 partials per block-column
  #pragma unroll
  for (int nt = 0; nt < 2; nt++) {
    redS[contrib][wn * 64 + nt * 32 + l31] = ps[nt];
    redQ[contrib][wn * 64 + nt * 32 + l31] = pq[nt];
  }
  __syncthreads();
  if (tid < 256) {
    int ssum = 0; long long sq = 0;
    #pragma unroll
    for (int t = 0; t < 4; t++) { ssum += redS[t][tid]; sq += (long long)redQ[t][tid]; }
    atomicAdd(&colsum[col0 + tid], ssum);
    atomicAdd(&colsq[col0 + tid], (u64)sq);
  }
  if (dominmax) {
    __syncthreads();
    #pragma unroll
    for (int nt = 0; nt < 2; nt++) {
      redS[contrib][wn * 64 + nt * 32 + l31] = mx[nt];
      redQ[contrib][wn * 64 + nt * 32 + l31] = mn[nt];
    }
    __syncthreads();
    if (tid < 256) {
      int m1 = -100000, m2 = 100000;
      #pragma unroll
      for (int t = 0; t < 4; t++) {
        m1 = (redS[t][tid] > m1) ? redS[t][tid] : m1;
        m2 = (redQ[t][tid] < m2) ? redQ[t][tid] : m2;
      }
      atomicMax(&colmax[col0 + tid], m1);
      atomicMin(&colmin[col0 + tid], m2);
    }
  }
}

// ---------------- per-column scale c = gamma / sqrt(var + eps) ----------------
__global__ void stats01(const int* __restrict__ colsum, const u64* __restrict__ colsq,
                        const float* __restrict__ gamma, int layer, float* __restrict__ c) {
  int n = blockIdx.x * 256 + threadIdx.x;
  double mu  = (double)colsum[n] / 8192.0;
  double var = (double)colsq[n] / 8192.0 - mu * mu;
  c[n] = (float)((double)gamma[layer] / sqrt(var + 1e-5));
}

// -------- binarize BN output -> next-layer bits (+ fused row-popcount) --------
__global__ void binarize_pack(const short* __restrict__ S, const int* __restrict__ colsum,
                              const float* __restrict__ c, const float* __restrict__ beta,
                              int layer, u64* __restrict__ bits, int* __restrict__ rpn) {
  int gwave = (blockIdx.x * 256 + threadIdx.x) >> 6;
  int lane = threadIdx.x & 63;
  int idx0 = (gwave << 7) + lane;
  int idx1 = idx0 + 64;
  int n0 = idx0 & (K_BITS - 1);
  int n1 = idx1 & (K_BITS - 1);
  float bv = beta[layer];
  int t0 = (int)S[idx0] * 8192 - colsum[n0];
  int t1 = (int)S[idx1] * 8192 - colsum[n1];
  float a0 = (float)t0 * c[n0] * (1.0f / 8192.0f) + bv;
  float a1 = (float)t1 * c[n1] * (1.0f / 8192.0f) + bv;
  u64 m0 = __ballot(a0 >= 0.0f);
  u64 m1 = __ballot(a1 >= 0.0f);
  if (lane == 0) {
    bits[(gwave << 1) + 0] = m0;
    bits[(gwave << 1) + 1] = m1;
    atomicAdd(&rpn[idx0 >> 12], (int)(__popcll(m0) + __popcll(m1)));  // same row
  }
}

// ---------------- last-layer stats: scale + reference s for softmax ------------
__global__ void final_stats(const int* __restrict__ colsum, const u64* __restrict__ colsq,
                            const int* __restrict__ colmax, const int* __restrict__ colmin,
                            const float* __restrict__ gamma,
                            float* __restrict__ c, int* __restrict__ sref) {
  int n = blockIdx.x * 256 + threadIdx.x;  // 1024
  double mu  = (double)colsum[n] / 8192.0;
  double var = (double)colsq[n] / 8192.0 - mu * mu;
  float cv = (float)((double)gamma[2] / sqrt(var + 1e-5));
  c[n] = cv;
  sref[n] = (cv >= 0.0f) ? colmax[n] : colmin[n];   // argmax of a per column
}

// ---------------- softmax over batch dim (axis 0), per column ----------------
__global__ void softmax_p1(const short* __restrict__ S2, const int* __restrict__ sref,
                           const float* __restrict__ c, float* __restrict__ out,
                           float* __restrict__ esum) {
  int n  = blockIdx.x * 256 + threadIdx.x;   // gridDim.x = 4 -> n in [0,1024)
  int r0 = blockIdx.y * 128;
  float cs = c[n]; int sr = sref[n];
  float acc = 0.0f;
  for (int r = 0; r < 128; r++) {
    size_t idx = (size_t)(r0 + r) * 1024 + n;
    float e = __expf((float)((int)S2[idx] - sr) * cs);   // (a - amax), always <= 0
    out[idx] = e;
    acc += e;
  }
  atomicAdd(&esum[n], acc);
}

__global__ void softmax_p2(float* __restrict__ out, const float* __restrict__ esum) {
  int idx = blockIdx.x * 256 + threadIdx.x;
  out[idx] /= esum[idx & 1023];
}

// ---------------- launcher ----------------
extern "C" void kernel_launch(void* const* d_in, const int* in_sizes, int n_in,
                              void* d_out, int out_size, void* d_ws, size_t ws_size,
                              hipStream_t stream) {
  const float* x     = (const float*)d_in[0];
  const float* W0    = (const float*)d_in[1];
  const float* W1    = (const float*)d_in[2];
  const float* W2    = (const float*)d_in[3];
  const float* gamma = (const float*)d_in[4];
  const float* beta  = (const float*)d_in[5];
  float* out = (float*)d_out;

  char* ws = (char*)d_ws;
  u64*   bitsA = (u64*)(ws + 0);                  // 4 MiB  (8192 x 64 u64)
  u64*   bitsB = (u64*)(ws + (4ull  << 20));      // 4 MiB
  u64*   Wb0   = (u64*)(ws + (8ull  << 20));      // 2 MiB  (4096 x 64 u64)
  u64*   Wb1   = (u64*)(ws + (10ull << 20));      // 2 MiB
  u64*   Wb2   = (u64*)(ws + (12ull << 20));      // 0.5 MiB (1024 x 64 u64)
  short* S     = (short*)(ws + (16ull << 20));    // 64 MiB (8192 x 4096 int16)
  char*  st    = ws + (80ull << 20);
  int*   sum0 = (int*)(st);                        // 16 KB
  u64*   sq0  = (u64*)(st + 16 * 1024);            // 32 KB
  int*   sum1 = (int*)(st + 48 * 1024);            // 16 KB
  u64*   sq1  = (u64*)(st + 64 * 1024);            // 32 KB
  int*   sum2 = (int*)(st + 96 * 1024);            // 4 KB
  u64*   sq2  = (u64*)(st + 100 * 1024);           // 8 KB
  int*   smax = (int*)(st + 108 * 1024);           // 4 KB
  int*   smin = (int*)(st + 112 * 1024);           // 4 KB
  float* c0   = (float*)(st + 116 * 1024);         // 16 KB
  float* c1   = (float*)(st + 132 * 1024);         // 16 KB
  float* c2   = (float*)(st + 148 * 1024);         // 4 KB
  int*   sref = (int*)(st + 152 * 1024);           // 4 KB
  float* esum = (float*)(st + 156 * 1024);         // 4 KB
  int*   rp0  = (int*)(st + 160 * 1024);           // 32 KB (row popcount, layer0 in)
  int*   rp1  = (int*)(st + 192 * 1024);           // 32 KB (layer1 in)
  int*   rp2  = (int*)(st + 224 * 1024);           // 32 KB (layer2 in)
  int*   cp0  = (int*)(st + 256 * 1024);           // 16 KB (col popcount W0)
  int*   cp1  = (int*)(st + 272 * 1024);           // 16 KB
  int*   cp2  = (int*)(st + 288 * 1024);           // 4 KB

  init_stats<<<32, 256, 0, stream>>>(sum0, sq0, sum1, sq1, sum2, sq2, smax, smin, esum,
                                     rp0, rp1, rp2, cp0, cp1, cp2);
  pack_x<<<B_ROWS, 256, 0, stream>>>(x, bitsA, rp0);
  pack_w<<<(4096 * 64) / 256, 256, 0, stream>>>(W0, Wb0, 4096, 12, cp0);
  pack_w<<<(4096 * 64) / 256, 256, 0, stream>>>(W1, Wb1, 4096, 12, cp1);
  pack_w<<<(1024 * 64) / 256, 256, 0, stream>>>(W2, Wb2, 1024, 10, cp2);

  // layer 0
  gemm_mfma<<<dim3(16, 32), 512, 0, stream>>>(bitsA, Wb0, S, 4096, rp0, cp0,
                                              sum0, sq0, nullptr, nullptr, 0);
  stats01<<<16, 256, 0, stream>>>(sum0, sq0, gamma, 0, c0);
  binarize_pack<<<(B_ROWS * 4096) / 512, 256, 0, stream>>>(S, sum0, c0, beta, 0, bitsB, rp1);

  // layer 1
  gemm_mfma<<<dim3(16, 32), 512, 0, stream>>>(bitsB, Wb1, S, 4096, rp1, cp1,
                                              sum1, sq1, nullptr, nullptr, 0);
  stats01<<<16, 256, 0, stream>>>(sum1, sq1, gamma, 1, c1);
  binarize_pack<<<(B_ROWS * 4096) / 512, 256, 0, stream>>>(S, sum1, c1, beta, 1, bitsA, rp2);

  // layer 2 (N=1024) + batch-dim softmax
  gemm_mfma<<<dim3(4, 32), 512, 0, stream>>>(bitsA, Wb2, S, 1024, rp2, cp2,
                                             sum2, sq2, smax, smin, 1);
  final_stats<<<4, 256, 0, stream>>>(sum2, sq2, smax, smin, gamma, c2, sref);
  softmax_p1<<<dim3(4, 64), 256, 0, stream>>>(S, sref, c2, out, esum);
  softmax_p2<<<(B_ROWS * 1024) / 256, 256, 0, stream>>>(out, esum);
}

// Round 6
// 765.714 us; speedup vs baseline: 1.1912x; 1.0085x over previous
//
#include <hip/hip_runtime.h>
#include <stdint.h>

typedef unsigned long long u64;
typedef int v4i  __attribute__((ext_vector_type(4)));
typedef int v16i __attribute__((ext_vector_type(16)));

#define B_ROWS 8192
#define K_BITS 4096
#define KW 64      // u64 words along K (4096/64)
#define GBM 128    // block tile rows
#define GBN 128    // block tile cols

// ---------------- init ----------------
__global__ void init_stats(int* sum0, u64* sq0, int* sum1, u64* sq1,
                           int* sum2, u64* sq2, int* smax, int* smin, float* esum,
                           int* rp0, int* rp1, int* rp2, int* cp0, int* cp1, int* cp2) {
  int i = blockIdx.x * 256 + threadIdx.x;   // grid 32x256 = 8192
  if (i < 8192) { rp0[i] = 0; rp1[i] = 0; rp2[i] = 0; }
  if (i < 4096) { sum0[i] = 0; sq0[i] = 0; sum1[i] = 0; sq1[i] = 0; cp0[i] = 0; cp1[i] = 0; }
  if (i < 1024) {
    sum2[i] = 0; sq2[i] = 0; cp2[i] = 0;
    smax[i] = (int)0x80000000; smin[i] = 0x7fffffff;
    esum[i] = 0.0f;
  }
}

// ---------------- binarize + bit-pack x (+ fused row-popcount) ----------------
// One block per row: thread t packs 16 consecutive floats (4x float4, 16B/lane)
// into a ushort; little-endian ushort view of the u64 bit array preserves the
// layout bits[row*64 + col/64] bit (col&63). Row popcount: wave shfl-reduce +
// LDS, single direct store (no atomics).
__global__ __launch_bounds__(256)
void pack_x(const float* __restrict__ x, u64* __restrict__ bits,
            int* __restrict__ rp) {
  const int row = blockIdx.x;
  const int t = threadIdx.x;
  const float4* p = (const float4*)(x + (size_t)row * K_BITS + 16 * t);
  unsigned m = 0;
  #pragma unroll
  for (int q = 0; q < 4; q++) {
    float4 v = p[q];
    m |= (unsigned)(v.x >= 0.5f) << (4 * q + 0);
    m |= (unsigned)(v.y >= 0.5f) << (4 * q + 1);
    m |= (unsigned)(v.z >= 0.5f) << (4 * q + 2);
    m |= (unsigned)(v.w >= 0.5f) << (4 * q + 3);
  }
  ((unsigned short*)bits)[(size_t)row * 256 + t] = (unsigned short)m;
  int pc = __popc(m);
  #pragma unroll
  for (int off = 32; off; off >>= 1) pc += __shfl_down(pc, off);   // wave64 reduce
  __shared__ int acc4[4];
  if ((t & 63) == 0) acc4[t >> 6] = pc;
  __syncthreads();
  if (t == 0) rp[row] = acc4[0] + acc4[1] + acc4[2] + acc4[3];
}

// ------- binarize + transpose-pack W (K x N -> [N][KW] bits) + col-popcount ----
__global__ void pack_w(const float* __restrict__ W, u64* __restrict__ Wb,
                       int N, int nlog2, int* __restrict__ cp) {
  int t = blockIdx.x * 256 + threadIdx.x;   // N*64 threads
  int n = t & (N - 1);
  int w = t >> nlog2;
  const float* p = W + (size_t)(w * 64) * N + n;
  u64 m = 0;
  #pragma unroll 8
  for (int b = 0; b < 64; b++)
    m |= (u64)(p[(size_t)b * N] >= 0.0f) << b;
  Wb[(size_t)n * KW + w] = m;
  atomicAdd(&cp[n], (int)__popcll(m));
}

// 16 bits (0/1) -> 16 i8 bytes in 4 VGPRs. bit q*4+j -> reg q, byte j.
// spread: (nib * 0x00204081) & 0x01010101 puts nibble bit i into byte i LSB.
__device__ __forceinline__ v4i unpack16(unsigned word, int shbase) {
  v4i r;
  #pragma unroll
  for (int q = 0; q < 4; q++) {
    unsigned nib = (word >> (shbase + 4 * q)) & 15u;
    r[q] = (int)(__umul24(nib, 0x00204081u) & 0x01010101u);
  }
  return r;
}

// ---------------- MFMA-i8 binary GEMM + fused column stats ----------------
// s[r][n] = 4*dot01 - 2*rowpop[r] - 2*colpop[n] + 4096  (a,w in {-1,+1})
// 128x128 tile, 256 thr = 4 waves (2M x 2N); per wave 64x64 out = 2x2 MFMA
// tiles of 32x32, acc 64 i32/lane (occupancy lever: round-5's 128-acc layout
// capped at 2 waves/SIMD; this targets 4 waves/SIMD under launch_bounds(256,4)).
// Bits staged in LDS (4KB/chunk of K=128), register-double-buffered global
// loads; fragments unpacked in-register (same per-lane formulas as the
// verified round-4 kernel).
// A/B frag layout: lane l -> row/col = l&31, k = 16*(l>>5)+e, e=4*reg+byte.
// C/D layout (m74/m101-verified): col=lane&31, row=(reg&3)+8*(reg>>2)+4*(lane>>5).
__global__ __launch_bounds__(256, 4)
void gemm_mfma(const u64* __restrict__ Ab, const u64* __restrict__ Wb,
               short* __restrict__ S, int N,
               const int* __restrict__ rp, const int* __restrict__ cp,
               int* __restrict__ colsum, u64* __restrict__ colsq,
               int* __restrict__ colmax, int* __restrict__ colmin, int dominmax) {
  __shared__ alignas(16) u64 AsB[128][2];   // 2 KB: bit chunk (K=128) for A rows
  __shared__ alignas(16) u64 BsB[128][2];   // 2 KB: bit chunk for B cols
  __shared__ int rp_s[128];
  __shared__ int redS[4][128];
  __shared__ int redQ[4][128];

  const int tid  = threadIdx.x;
  const int lane = tid & 63;
  const int wid  = tid >> 6;          // 0..3
  const int wm   = wid >> 1;          // 0..1 (M)
  const int wn   = wid & 1;           // 0..1 (N)
  const int half = lane >> 5;         // 0..1
  const int l31  = lane & 31;
  const int row0 = blockIdx.y * GBM, col0 = blockIdx.x * GBN;

  if (tid < 128) rp_s[tid] = rp[row0 + tid];

  v16i acc[2][2];
  #pragma unroll
  for (int mt = 0; mt < 2; mt++)
    #pragma unroll
    for (int nt = 0; nt < 2; nt++)
      #pragma unroll
      for (int e = 0; e < 16; e++) acc[mt][nt][e] = 0;

  // staging: thread t owns (row=t>>1, word=t&1); 128 rows x 2 u64 = 256 slots
  const int srow = tid >> 1, sw = tid & 1;
  const u64* aptr = Ab + (size_t)(row0 + srow) * KW + sw;
  const u64* bptr = Wb + (size_t)(col0 + srow) * KW + sw;

  u64 areg = aptr[0], breg = bptr[0];

  for (int ch = 0; ch < 32; ch++) {
    AsB[srow][sw] = areg;
    BsB[srow][sw] = breg;
    __syncthreads();
    if (ch < 31) { areg = aptr[2 * (ch + 1)]; breg = bptr[2 * (ch + 1)]; }
    // pull this wave's bit words to registers, then release LDS at barrier
    uint4 abits[2], bbits[2];
    #pragma unroll
    for (int mt = 0; mt < 2; mt++)
      abits[mt] = *(const uint4*)&AsB[wm * 64 + mt * 32 + l31][0];
    #pragma unroll
    for (int nt = 0; nt < 2; nt++)
      bbits[nt] = *(const uint4*)&BsB[wn * 64 + nt * 32 + l31][0];
    __syncthreads();
    // 4 k-steps of 32; compute is register-only (overlaps next-chunk staging)
    #pragma unroll
    for (int ks = 0; ks < 4; ks++) {
      v4i afrag[2], bfrag[2];
      #pragma unroll
      for (int mt = 0; mt < 2; mt++) {
        unsigned wa = (ks == 0) ? abits[mt].x : (ks == 1) ? abits[mt].y
                    : (ks == 2) ? abits[mt].z : abits[mt].w;
        afrag[mt] = unpack16(wa, half * 16);
      }
      #pragma unroll
      for (int nt = 0; nt < 2; nt++) {
        unsigned wb = (ks == 0) ? bbits[nt].x : (ks == 1) ? bbits[nt].y
                    : (ks == 2) ? bbits[nt].z : bbits[nt].w;
        bfrag[nt] = unpack16(wb, half * 16);
      }
      #pragma unroll
      for (int mt = 0; mt < 2; mt++)
        #pragma unroll
        for (int nt = 0; nt < 2; nt++)
          acc[mt][nt] = __builtin_amdgcn_mfma_i32_32x32x32_i8(
              afrag[mt], bfrag[nt], acc[mt][nt], 0, 0, 0);
    }
  }

  // ---- epilogue: s = 4*acc - 2*rp - 2*cp + 4096; write S + column partials ----
  int cpv[2];
  #pragma unroll
  for (int nt = 0; nt < 2; nt++) cpv[nt] = cp[col0 + wn * 64 + nt * 32 + l31];

  int ps[2], pq[2], mx[2], mn[2];
  #pragma unroll
  for (int nt = 0; nt < 2; nt++) { ps[nt] = 0; pq[nt] = 0; mx[nt] = -100000; mn[nt] = 100000; }

  #pragma unroll
  for (int mt = 0; mt < 2; mt++) {
    #pragma unroll
    for (int reg = 0; reg < 16; reg++) {
      int rloc = wm * 64 + mt * 32 + (reg & 3) + 8 * (reg >> 2) + 4 * half;
      int rpv  = rp_s[rloc];
      size_t rowoff = (size_t)(row0 + rloc) * N + col0;
      #pragma unroll
      for (int nt = 0; nt < 2; nt++) {
        int s = 4 * acc[mt][nt][reg] - 2 * rpv - 2 * cpv[nt] + K_BITS;
        S[rowoff + wn * 64 + nt * 32 + l31] = (short)s;
        ps[nt] += s;
        pq[nt] += s * s;   // 32 * 4096^2 = 5.4e8 < 2^31
        mx[nt] = (s > mx[nt]) ? s : mx[nt];
        mn[nt] = (s < mn[nt]) ? s : mn[nt];
      }
    }
  }

  const int contrib = wm * 2 + half;   // 4 partials per block-column
  #pragma unroll
  for (int nt = 0; nt < 2; nt++) {
    redS[contrib][wn * 64 + nt * 32 + l31] = ps[nt];
    redQ[contrib][wn * 64 + nt * 32 + l31] = pq[nt];
  }
  __syncthreads();
  if (tid < 128) {
    int ssum = 0; long long sq = 0;
    #pragma unroll
    for (int t = 0; t < 4; t++) { ssum += redS[t][tid]; sq += (long long)redQ[t][tid]; }
    atomicAdd(&colsum[col0 + tid], ssum);
    atomicAdd(&colsq[col0 + tid], (u64)sq);
  }
  if (dominmax) {
    __syncthreads();
    #pragma unroll
    for (int nt = 0; nt < 2; nt++) {
      redS[contrib][wn * 64 + nt * 32 + l31] = mx[nt];
      redQ[contrib][wn * 64 + nt * 32 + l31] = mn[nt];
    }
    __syncthreads();
    if (tid < 128) {
      int m1 = -100000, m2 = 100000;
      #pragma unroll
      for (int t = 0; t < 4; t++) {
        m1 = (redS[t][tid] > m1) ? redS[t][tid] : m1;
        m2 = (redQ[t][tid] < m2) ? redQ[t][tid] : m2;
      }
      atomicMax(&colmax[col0 + tid], m1);
      atomicMin(&colmin[col0 + tid], m2);
    }
  }
}

// ---------------- per-column scale c = gamma / sqrt(var + eps) ----------------
__global__ void stats01(const int* __restrict__ colsum, const u64* __restrict__ colsq,
                        const float* __restrict__ gamma, int layer, float* __restrict__ c) {
  int n = blockIdx.x * 256 + threadIdx.x;
  double mu  = (double)colsum[n] / 8192.0;
  double var = (double)colsq[n] / 8192.0 - mu * mu;
  c[n] = (float)((double)gamma[layer] / sqrt(var + 1e-5));
}

// -------- binarize BN output -> next-layer bits (+ fused row-popcount) --------
__global__ void binarize_pack(const short* __restrict__ S, const int* __restrict__ colsum,
                              const float* __restrict__ c, const float* __restrict__ beta,
                              int layer, u64* __restrict__ bits, int* __restrict__ rpn) {
  int gwave = (blockIdx.x * 256 + threadIdx.x) >> 6;
  int lane = threadIdx.x & 63;
  int idx0 = (gwave << 7) + lane;
  int idx1 = idx0 + 64;
  int n0 = idx0 & (K_BITS - 1);
  int n1 = idx1 & (K_BITS - 1);
  float bv = beta[layer];
  int t0 = (int)S[idx0] * 8192 - colsum[n0];
  int t1 = (int)S[idx1] * 8192 - colsum[n1];
  float a0 = (float)t0 * c[n0] * (1.0f / 8192.0f) + bv;
  float a1 = (float)t1 * c[n1] * (1.0f / 8192.0f) + bv;
  u64 m0 = __ballot(a0 >= 0.0f);
  u64 m1 = __ballot(a1 >= 0.0f);
  if (lane == 0) {
    bits[(gwave << 1) + 0] = m0;
    bits[(gwave << 1) + 1] = m1;
    atomicAdd(&rpn[idx0 >> 12], (int)(__popcll(m0) + __popcll(m1)));  // same row
  }
}

// ---------------- last-layer stats: scale + reference s for softmax ------------
__global__ void final_stats(const int* __restrict__ colsum, const u64* __restrict__ colsq,
                            const int* __restrict__ colmax, const int* __restrict__ colmin,
                            const float* __restrict__ gamma,
                            float* __restrict__ c, int* __restrict__ sref) {
  int n = blockIdx.x * 256 + threadIdx.x;  // 1024
  double mu  = (double)colsum[n] / 8192.0;
  double var = (double)colsq[n] / 8192.0 - mu * mu;
  float cv = (float)((double)gamma[2] / sqrt(var + 1e-5));
  c[n] = cv;
  sref[n] = (cv >= 0.0f) ? colmax[n] : colmin[n];   // argmax of a per column
}

// ---------------- softmax over batch dim (axis 0), per column ----------------
__global__ void softmax_p1(const short* __restrict__ S2, const int* __restrict__ sref,
                           const float* __restrict__ c, float* __restrict__ out,
                           float* __restrict__ esum) {
  int n  = blockIdx.x * 256 + threadIdx.x;   // gridDim.x = 4 -> n in [0,1024)
  int r0 = blockIdx.y * 128;
  float cs = c[n]; int sr = sref[n];
  float acc = 0.0f;
  for (int r = 0; r < 128; r++) {
    size_t idx = (size_t)(r0 + r) * 1024 + n;
    float e = __expf((float)((int)S2[idx] - sr) * cs);   // (a - amax), always <= 0
    out[idx] = e;
    acc += e;
  }
  atomicAdd(&esum[n], acc);
}

__global__ void softmax_p2(float* __restrict__ out, const float* __restrict__ esum) {
  int idx = blockIdx.x * 256 + threadIdx.x;
  out[idx] /= esum[idx & 1023];
}

// ---------------- launcher ----------------
extern "C" void kernel_launch(void* const* d_in, const int* in_sizes, int n_in,
                              void* d_out, int out_size, void* d_ws, size_t ws_size,
                              hipStream_t stream) {
  const float* x     = (const float*)d_in[0];
  const float* W0    = (const float*)d_in[1];
  const float* W1    = (const float*)d_in[2];
  const float* W2    = (const float*)d_in[3];
  const float* gamma = (const float*)d_in[4];
  const float* beta  = (const float*)d_in[5];
  float* out = (float*)d_out;

  char* ws = (char*)d_ws;
  u64*   bitsA = (u64*)(ws + 0);                  // 4 MiB  (8192 x 64 u64)
  u64*   bitsB = (u64*)(ws + (4ull  << 20));      // 4 MiB
  u64*   Wb0   = (u64*)(ws + (8ull  << 20));      // 2 MiB  (4096 x 64 u64)
  u64*   Wb1   = (u64*)(ws + (10ull << 20));      // 2 MiB
  u64*   Wb2   = (u64*)(ws + (12ull << 20));      // 0.5 MiB (1024 x 64 u64)
  short* S     = (short*)(ws + (16ull << 20));    // 64 MiB (8192 x 4096 int16)
  char*  st    = ws + (80ull << 20);
  int*   sum0 = (int*)(st);                        // 16 KB
  u64*   sq0  = (u64*)(st + 16 * 1024);            // 32 KB
  int*   sum1 = (int*)(st + 48 * 1024);            // 16 KB
  u64*   sq1  = (u64*)(st + 64 * 1024);            // 32 KB
  int*   sum2 = (int*)(st + 96 * 1024);            // 4 KB
  u64*   sq2  = (u64*)(st + 100 * 1024);           // 8 KB
  int*   smax = (int*)(st + 108 * 1024);           // 4 KB
  int*   smin = (int*)(st + 112 * 1024);           // 4 KB
  float* c0   = (float*)(st + 116 * 1024);         // 16 KB
  float* c1   = (float*)(st + 132 * 1024);         // 16 KB
  float* c2   = (float*)(st + 148 * 1024);         // 4 KB
  int*   sref = (int*)(st + 152 * 1024);           // 4 KB
  float* esum = (float*)(st + 156 * 1024);         // 4 KB
  int*   rp0  = (int*)(st + 160 * 1024);           // 32 KB (row popcount, layer0 in)
  int*   rp1  = (int*)(st + 192 * 1024);           // 32 KB (layer1 in)
  int*   rp2  = (int*)(st + 224 * 1024);           // 32 KB (layer2 in)
  int*   cp0  = (int*)(st + 256 * 1024);           // 16 KB (col popcount W0)
  int*   cp1  = (int*)(st + 272 * 1024);           // 16 KB
  int*   cp2  = (int*)(st + 288 * 1024);           // 4 KB

  init_stats<<<32, 256, 0, stream>>>(sum0, sq0, sum1, sq1, sum2, sq2, smax, smin, esum,
                                     rp0, rp1, rp2, cp0, cp1, cp2);
  pack_x<<<B_ROWS, 256, 0, stream>>>(x, bitsA, rp0);
  pack_w<<<(4096 * 64) / 256, 256, 0, stream>>>(W0, Wb0, 4096, 12, cp0);
  pack_w<<<(4096 * 64) / 256, 256, 0, stream>>>(W1, Wb1, 4096, 12, cp1);
  pack_w<<<(1024 * 64) / 256, 256, 0, stream>>>(W2, Wb2, 1024, 10, cp2);

  // layer 0
  gemm_mfma<<<dim3(32, 64), 256, 0, stream>>>(bitsA, Wb0, S, 4096, rp0, cp0,
                                              sum0, sq0, nullptr, nullptr, 0);
  stats01<<<16, 256, 0, stream>>>(sum0, sq0, gamma, 0, c0);
  binarize_pack<<<(B_ROWS * 4096) / 512, 256, 0, stream>>>(S, sum0, c0, beta, 0, bitsB, rp1);

  // layer 1
  gemm_mfma<<<dim3(32, 64), 256, 0, stream>>>(bitsB, Wb1, S, 4096, rp1, cp1,
                                              sum1, sq1, nullptr, nullptr, 0);
  stats01<<<16, 256, 0, stream>>>(sum1, sq1, gamma, 1, c1);
  binarize_pack<<<(B_ROWS * 4096) / 512, 256, 0, stream>>>(S, sum1, c1, beta, 1, bitsA, rp2);

  // layer 2 (N=1024) + batch-dim softmax
  gemm_mfma<<<dim3(8, 64), 256, 0, stream>>>(bitsA, Wb2, S, 1024, rp2, cp2,
                                             sum2, sq2, smax, smin, 1);
  final_stats<<<4, 256, 0, stream>>>(sum2, sq2, smax, smin, gamma, c2, sref);
  softmax_p1<<<dim3(4, 64), 256, 0, stream>>>(S, sref, c2, out, esum);
  softmax_p2<<<(B_ROWS * 1024) / 256, 256, 0, stream>>>(out, esum);
}